// Round 1
// baseline (1560.422 us; speedup 1.0000x reference)
//
#include <hip/hip_runtime.h>
#include <hip/hip_bf16.h>

#define N_NODES 50000
#define N_EDGES 800000
#define N_REL   4
#define D       128

// ---------------------------------------------------------------------------
// ws layout:
//   [0, 800000)                 : deg / inv_sqrt  (4 * 50000 f32)
//   [800000, 800000+102400000)  : Y = X @ W_r     (4 * 50000 * 128 f32)
// total ~103.2 MB
// ---------------------------------------------------------------------------
#define DEG_BYTES (N_REL * N_NODES * sizeof(float))

// deg[r][i] = sum of vals over edges with rows == i   (3.2M f32 atomics)
__global__ __launch_bounds__(256) void k_deg(const int* __restrict__ rows,
                                             const float* __restrict__ vals,
                                             float* __restrict__ deg) {
    int t = blockIdx.x * 256 + threadIdx.x;
    if (t >= N_REL * N_EDGES) return;
    int r = t / N_EDGES;
    unsafeAtomicAdd(&deg[r * N_NODES + rows[t]], vals[t]);
}

// deg -> rsqrt(max(deg, 1e-12))
__global__ __launch_bounds__(256) void k_rsqrt(float* __restrict__ deg) {
    int t = blockIdx.x * 256 + threadIdx.x;
    if (t < N_REL * N_NODES) deg[t] = rsqrtf(fmaxf(deg[t], 1e-12f));
}

// Fused 5-panel GEMM: seg 0 -> out = X@W_self + bias ; seg r -> Y[r-1] = X@W_rel[r-1]
// M=50000, K=128, N=128 per panel. BM=64, BN=128, BK=32. 256 threads.
__global__ __launch_bounds__(256) void k_gemm(const float* __restrict__ X,
                                              const float* __restrict__ Wself,
                                              const float* __restrict__ Wrel,
                                              const float* __restrict__ bias,
                                              float* __restrict__ out,
                                              float* __restrict__ Y) {
    const int seg = blockIdx.y;
    const float* __restrict__ W = (seg == 0) ? Wself : (Wrel + (size_t)(seg - 1) * D * D);
    float* __restrict__ dst = (seg == 0) ? out : (Y + (size_t)(seg - 1) * N_NODES * D);

    const int tid = threadIdx.x;
    const int tx = tid & 31;   // column group: float4 at tx*4
    const int ty = tid >> 5;   // row group: rows ty + 8*i
    const int m0 = blockIdx.x * 64;

    __shared__ float Xs[64][36];   // pad to 36 so float4 stores stay 16B-aligned
    __shared__ float Ws[32][128];

    float acc[8][4];
#pragma unroll
    for (int i = 0; i < 8; i++)
#pragma unroll
        for (int j = 0; j < 4; j++) acc[i][j] = 0.f;

    for (int k0 = 0; k0 < D; k0 += 32) {
        // stage X tile: 64 rows x 32 k  (512 float4s, 2 per thread)
#pragma unroll
        for (int l = 0; l < 2; l++) {
            int id4 = tid + l * 256;
            int row = id4 >> 3;          // 8 float4 per row
            int c4  = id4 & 7;
            int grow = m0 + row;
            float4 v = make_float4(0.f, 0.f, 0.f, 0.f);
            if (grow < N_NODES)
                v = *(const float4*)(X + (size_t)grow * D + k0 + c4 * 4);
            *(float4*)&Xs[row][c4 * 4] = v;
        }
        // stage W tile: 32 k x 128 cols (1024 float4s, 4 per thread)
#pragma unroll
        for (int l = 0; l < 4; l++) {
            int id4 = tid + l * 256;
            int row = id4 >> 5;          // 32 float4 per row
            int c4  = id4 & 31;
            *(float4*)&Ws[row][c4 * 4] =
                *(const float4*)(W + (size_t)(k0 + row) * D + c4 * 4);
        }
        __syncthreads();

#pragma unroll
        for (int kk = 0; kk < 32; ++kk) {
            float4 b = *(const float4*)&Ws[kk][tx * 4];
            float a[8];
#pragma unroll
            for (int i = 0; i < 8; i++) a[i] = Xs[ty + i * 8][kk];
#pragma unroll
            for (int i = 0; i < 8; i++) {
                acc[i][0] += a[i] * b.x;
                acc[i][1] += a[i] * b.y;
                acc[i][2] += a[i] * b.z;
                acc[i][3] += a[i] * b.w;
            }
        }
        __syncthreads();
    }

    float4 bv = make_float4(0.f, 0.f, 0.f, 0.f);
    if (seg == 0) bv = *(const float4*)(bias + tx * 4);
#pragma unroll
    for (int i = 0; i < 8; i++) {
        int grow = m0 + ty + i * 8;
        if (grow < N_NODES) {
            float4 o = make_float4(acc[i][0] + bv.x, acc[i][1] + bv.y,
                                   acc[i][2] + bv.z, acc[i][3] + bv.w);
            *(float4*)(dst + (size_t)grow * D + tx * 4) = o;
        }
    }
}

// Edge scatter: one 64-lane wave per edge.
// out[row][:] += v*inv[row]*inv[col] * Y[r][col][:]
__global__ __launch_bounds__(256) void k_scatter(const int* __restrict__ rows,
                                                 const int* __restrict__ cols,
                                                 const float* __restrict__ vals,
                                                 const float* __restrict__ inv,
                                                 const float* __restrict__ Y,
                                                 float* __restrict__ out) {
    const int wid  = threadIdx.x >> 6;
    const int lane = threadIdx.x & 63;
    const long long ge = (long long)blockIdx.x * 4 + wid;
    if (ge >= (long long)N_REL * N_EDGES) return;
    const int e = (int)ge;
    const int r = e / N_EDGES;
    const int row = rows[e];
    const int col = cols[e];
    const float coef = vals[e] * inv[r * N_NODES + row] * inv[r * N_NODES + col];

    const float* __restrict__ ysrc = Y + ((size_t)r * N_NODES + col) * D;
    float* __restrict__ dstp = out + (size_t)row * D;

    float v0 = ysrc[lane];
    float v1 = ysrc[lane + 64];
    unsafeAtomicAdd(dstp + lane,      coef * v0);
    unsafeAtomicAdd(dstp + lane + 64, coef * v1);
}

extern "C" void kernel_launch(void* const* d_in, const int* in_sizes, int n_in,
                              void* d_out, int out_size, void* d_ws, size_t ws_size,
                              hipStream_t stream) {
    const float* X     = (const float*)d_in[0];
    const int*   rows  = (const int*)d_in[1];
    const int*   cols  = (const int*)d_in[2];
    const float* vals  = (const float*)d_in[3];
    const float* Wrel  = (const float*)d_in[4];
    const float* Wself = (const float*)d_in[5];
    const float* bias  = (const float*)d_in[6];
    float* out = (float*)d_out;

    float* deg = (float*)d_ws;
    float* Y   = (float*)((char*)d_ws + DEG_BYTES);

    // zero deg accumulators (Y and out are fully overwritten by k_gemm)
    hipMemsetAsync(d_ws, 0, DEG_BYTES, stream);

    k_deg<<<(N_REL * N_EDGES + 255) / 256, 256, 0, stream>>>(rows, vals, deg);
    k_rsqrt<<<(N_REL * N_NODES + 255) / 256, 256, 0, stream>>>(deg);

    dim3 ggrid((N_NODES + 63) / 64, N_REL + 1);
    k_gemm<<<ggrid, 256, 0, stream>>>(X, Wself, Wrel, bias, out, Y);

    k_scatter<<<N_REL * N_EDGES / 4, 256, 0, stream>>>(rows, cols, vals, deg, Y, out);
}

// Round 2
// 858.943 us; speedup vs baseline: 1.8167x; 1.8167x over previous
//
#include <hip/hip_runtime.h>
#include <hip/hip_bf16.h>

#define N_NODES 50000
#define N_EDGES 800000
#define N_REL   4
#define D       128
#define NB      (N_REL * N_NODES)   // 200000 bins
#define NE      (N_REL * N_EDGES)   // 3200000 edges

#define SCAN_CHUNK 1024
#define NBLK ((NB + SCAN_CHUNK - 1) / SCAN_CHUNK)   // 196

// ---------------------------------------------------------------------------
// ws layout (bytes):
//   OFF_DEG   = 0          : deg / inv_sqrt   (200000 f32, 800 KB)
//   OFF_CNT   = 800000     : bin counts       (200000 i32, 800 KB)
//   OFF_CUR   = 1600000    : bin cursor       (200000 i32, 800 KB)
//   OFF_BSUM  = 2400000    : block sums       (196 i32)
//   OFF_BOFF  = 2401024    : block offsets    (196 i32)
//   OFF_EREC  = 2402048    : edge records     (3.2M int2, 25.6 MB)
//   OFF_Y     = 28002048   : Y bf16           (4*50000*128 bf16, 51.2 MB)
// total ~79.2 MB
// ---------------------------------------------------------------------------
#define OFF_DEG  0
#define OFF_CNT  800000
#define OFF_CUR  1600000
#define OFF_BSUM 2400000
#define OFF_BOFF 2401024
#define OFF_EREC 2402048
#define OFF_Y    28002048

__device__ inline unsigned short f2bf(float f) {
    unsigned u = __float_as_uint(f);
    u += 0x7fffu + ((u >> 16) & 1u);
    return (unsigned short)(u >> 16);
}

// histogram bins + degree sums (fused): 3.2M int + 3.2M f32 atomics, L2-resident
__global__ __launch_bounds__(256) void k_hist(const int* __restrict__ rows,
                                              const float* __restrict__ vals,
                                              float* __restrict__ deg,
                                              int* __restrict__ cnt) {
    int t = blockIdx.x * 256 + threadIdx.x;
    if (t >= NE) return;
    int r = t / N_EDGES;
    int bin = r * N_NODES + rows[t];
    atomicAdd(&cnt[bin], 1);
    unsafeAtomicAdd(&deg[bin], vals[t]);
}

__global__ __launch_bounds__(256) void k_rsqrt(float* __restrict__ deg) {
    int t = blockIdx.x * 256 + threadIdx.x;
    if (t < NB) deg[t] = rsqrtf(fmaxf(deg[t], 1e-12f));
}

// scan pass A: per-block (1024 elems) exclusive scan into cursor, block sum out
__global__ __launch_bounds__(256) void k_scanA(const int* __restrict__ cnt,
                                               int* __restrict__ cursor,
                                               int* __restrict__ bsum) {
    __shared__ int s[256];
    int t = threadIdx.x;
    int base = blockIdx.x * SCAN_CHUNK + t * 4;
    int v0 = 0, v1 = 0, v2 = 0, v3 = 0;
    if (base + 3 < NB) {
        int4 v = *(const int4*)(cnt + base);
        v0 = v.x; v1 = v.y; v2 = v.z; v3 = v.w;
    } else {
        if (base     < NB) v0 = cnt[base];
        if (base + 1 < NB) v1 = cnt[base + 1];
        if (base + 2 < NB) v2 = cnt[base + 2];
        if (base + 3 < NB) v3 = cnt[base + 3];
    }
    int tsum = v0 + v1 + v2 + v3;
    s[t] = tsum;
    __syncthreads();
    for (int off = 1; off < 256; off <<= 1) {
        int x = (t >= off) ? s[t - off] : 0;
        __syncthreads();
        s[t] += x;
        __syncthreads();
    }
    int excl = s[t] - tsum;
    if (base     < NB) cursor[base]     = excl;
    if (base + 1 < NB) cursor[base + 1] = excl + v0;
    if (base + 2 < NB) cursor[base + 2] = excl + v0 + v1;
    if (base + 3 < NB) cursor[base + 3] = excl + v0 + v1 + v2;
    if (t == 255) bsum[blockIdx.x] = s[255];
}

// scan pass B: scan the 196 block sums (single block)
__global__ __launch_bounds__(256) void k_scanB(const int* __restrict__ bsum,
                                               int* __restrict__ boff) {
    __shared__ int s[256];
    int t = threadIdx.x;
    int v = (t < NBLK) ? bsum[t] : 0;
    s[t] = v;
    __syncthreads();
    for (int off = 1; off < 256; off <<= 1) {
        int x = (t >= off) ? s[t - off] : 0;
        __syncthreads();
        s[t] += x;
        __syncthreads();
    }
    if (t < NBLK) boff[t] = s[t] - v;
}

// scan pass C: add block offsets
__global__ __launch_bounds__(256) void k_scanC(int* __restrict__ cursor,
                                               const int* __restrict__ boff) {
    int t = threadIdx.x;
    int base = blockIdx.x * SCAN_CHUNK + t * 4;
    int add = boff[blockIdx.x];
    if (base     < NB) cursor[base]     += add;
    if (base + 1 < NB) cursor[base + 1] += add;
    if (base + 2 < NB) cursor[base + 2] += add;
    if (base + 3 < NB) cursor[base + 3] += add;
}

// fill CSR records: (packed col idx, coef) per edge, positioned via cursor
__global__ __launch_bounds__(256) void k_fill(const int* __restrict__ rows,
                                              const int* __restrict__ cols,
                                              const float* __restrict__ vals,
                                              const float* __restrict__ inv,
                                              int* __restrict__ cursor,
                                              int2* __restrict__ erec) {
    int t = blockIdx.x * 256 + threadIdx.x;
    if (t >= NE) return;
    int r = t / N_EDGES;
    int row = rows[t], col = cols[t];
    float coef = vals[t] * inv[r * N_NODES + row] * inv[r * N_NODES + col];
    int bin = r * N_NODES + row;
    int pos = atomicAdd(&cursor[bin], 1);
    erec[pos] = make_int2(r * N_NODES + col, __float_as_int(coef));
}

// Fused 5-panel GEMM: seg 0 -> out = X@W_self + bias (f32); seg r -> Y[r-1] = X@W_rel[r-1] (bf16)
// M=50000, K=128, N=128. BM=64, BN=128, BK=32, 256 threads.
__global__ __launch_bounds__(256) void k_gemm(const float* __restrict__ X,
                                              const float* __restrict__ Wself,
                                              const float* __restrict__ Wrel,
                                              const float* __restrict__ bias,
                                              float* __restrict__ out,
                                              unsigned short* __restrict__ Yb) {
    const int seg = blockIdx.y;
    const float* __restrict__ W = (seg == 0) ? Wself : (Wrel + (size_t)(seg - 1) * D * D);

    const int tid = threadIdx.x;
    const int tx = tid & 31;   // column group: 4 cols at tx*4
    const int ty = tid >> 5;   // row group: rows ty + 8*i
    const int m0 = blockIdx.x * 64;

    __shared__ float Xs[64][36];
    __shared__ float Ws[32][128];

    float acc[8][4];
#pragma unroll
    for (int i = 0; i < 8; i++)
#pragma unroll
        for (int j = 0; j < 4; j++) acc[i][j] = 0.f;

    for (int k0 = 0; k0 < D; k0 += 32) {
#pragma unroll
        for (int l = 0; l < 2; l++) {
            int id4 = tid + l * 256;
            int row = id4 >> 3;
            int c4  = id4 & 7;
            int grow = m0 + row;
            float4 v = make_float4(0.f, 0.f, 0.f, 0.f);
            if (grow < N_NODES)
                v = *(const float4*)(X + (size_t)grow * D + k0 + c4 * 4);
            *(float4*)&Xs[row][c4 * 4] = v;
        }
#pragma unroll
        for (int l = 0; l < 4; l++) {
            int id4 = tid + l * 256;
            int row = id4 >> 5;
            int c4  = id4 & 31;
            *(float4*)&Ws[row][c4 * 4] =
                *(const float4*)(W + (size_t)(k0 + row) * D + c4 * 4);
        }
        __syncthreads();

#pragma unroll
        for (int kk = 0; kk < 32; ++kk) {
            float4 b = *(const float4*)&Ws[kk][tx * 4];
            float a[8];
#pragma unroll
            for (int i = 0; i < 8; i++) a[i] = Xs[ty + i * 8][kk];
#pragma unroll
            for (int i = 0; i < 8; i++) {
                acc[i][0] += a[i] * b.x;
                acc[i][1] += a[i] * b.y;
                acc[i][2] += a[i] * b.z;
                acc[i][3] += a[i] * b.w;
            }
        }
        __syncthreads();
    }

    if (seg == 0) {
        float4 bv = *(const float4*)(bias + tx * 4);
#pragma unroll
        for (int i = 0; i < 8; i++) {
            int grow = m0 + ty + i * 8;
            if (grow < N_NODES) {
                float4 o = make_float4(acc[i][0] + bv.x, acc[i][1] + bv.y,
                                       acc[i][2] + bv.z, acc[i][3] + bv.w);
                *(float4*)(out + (size_t)grow * D + tx * 4) = o;
            }
        }
    } else {
#pragma unroll
        for (int i = 0; i < 8; i++) {
            int grow = m0 + ty + i * 8;
            if (grow < N_NODES) {
                ushort4 h;
                h.x = f2bf(acc[i][0]);
                h.y = f2bf(acc[i][1]);
                h.z = f2bf(acc[i][2]);
                h.w = f2bf(acc[i][3]);
                *(ushort4*)(Yb + ((size_t)(seg - 1) * N_NODES + grow) * D + tx * 4) = h;
            }
        }
    }
}

// Gather: one wave per output row (4 waves/block). Lane covers cols 2l,2l+1.
// out[row] += sum over 4 relation bins of coef * Y[packed_col][:]
__global__ __launch_bounds__(256) void k_gather(const int* __restrict__ cursor,
                                                const int* __restrict__ cnt,
                                                const int2* __restrict__ erec,
                                                const unsigned int* __restrict__ Y2,
                                                float* __restrict__ out) {
    const int wid  = threadIdx.x >> 6;
    const int lane = threadIdx.x & 63;
    const int row  = blockIdx.x * 4 + wid;
    if (row >= N_NODES) return;

    float ax = 0.f, ay = 0.f;
#pragma unroll
    for (int r = 0; r < N_REL; r++) {
        const int bin = r * N_NODES + row;
        const int end = cursor[bin];          // fill advanced cursor to bin end
        int e = end - cnt[bin];
        for (; e < end; ++e) {
            int2 rec = erec[e];
            float coef = __int_as_float(rec.y);
            unsigned int y = Y2[(size_t)rec.x * 64 + lane];
            ax += coef * __uint_as_float(y << 16);
            ay += coef * __uint_as_float(y & 0xffff0000u);
        }
    }
    float2* op = (float2*)(out + (size_t)row * D) + lane;
    float2 o = *op;
    o.x += ax;
    o.y += ay;
    *op = o;
}

extern "C" void kernel_launch(void* const* d_in, const int* in_sizes, int n_in,
                              void* d_out, int out_size, void* d_ws, size_t ws_size,
                              hipStream_t stream) {
    const float* X     = (const float*)d_in[0];
    const int*   rows  = (const int*)d_in[1];
    const int*   cols  = (const int*)d_in[2];
    const float* vals  = (const float*)d_in[3];
    const float* Wrel  = (const float*)d_in[4];
    const float* Wself = (const float*)d_in[5];
    const float* bias  = (const float*)d_in[6];
    float* out = (float*)d_out;

    char* ws = (char*)d_ws;
    float* deg    = (float*)(ws + OFF_DEG);
    int*   cnt    = (int*)(ws + OFF_CNT);
    int*   cursor = (int*)(ws + OFF_CUR);
    int*   bsum   = (int*)(ws + OFF_BSUM);
    int*   boff   = (int*)(ws + OFF_BOFF);
    int2*  erec   = (int2*)(ws + OFF_EREC);
    unsigned short* Yb = (unsigned short*)(ws + OFF_Y);

    // zero deg + cnt (contiguous 1.6 MB)
    hipMemsetAsync(ws, 0, 2 * NB * sizeof(float), stream);

    k_hist<<<(NE + 255) / 256, 256, 0, stream>>>(rows, vals, deg, cnt);
    k_rsqrt<<<(NB + 255) / 256, 256, 0, stream>>>(deg);
    k_scanA<<<NBLK, 256, 0, stream>>>(cnt, cursor, bsum);
    k_scanB<<<1, 256, 0, stream>>>(bsum, boff);
    k_scanC<<<NBLK, 256, 0, stream>>>(cursor, boff);

    dim3 ggrid((N_NODES + 63) / 64, N_REL + 1);
    k_gemm<<<ggrid, 256, 0, stream>>>(X, Wself, Wrel, bias, out, Yb);

    k_fill<<<(NE + 255) / 256, 256, 0, stream>>>(rows, cols, vals, deg, cursor, erec);
    k_gather<<<(N_NODES + 3) / 4, 256, 0, stream>>>(cursor, cnt, erec,
                                                    (const unsigned int*)Yb, out);
}

// Round 3
// 628.003 us; speedup vs baseline: 2.4847x; 1.3677x over previous
//
#include <hip/hip_runtime.h>
#include <hip/hip_bf16.h>

#define N_NODES 50000
#define N_EDGES 800000
#define N_REL   4
#define D       128
#define NB      (N_REL * N_NODES)   // 200000 deg bins (per rel,row)
#define NE      (N_REL * N_EDGES)   // 3200000 edges
#define NBROW   N_NODES             // 50000 row bins

#define SCAN_CHUNK 1024
#define NBLK2 ((NBROW + SCAN_CHUNK - 1) / SCAN_CHUNK)   // 49

// ---------------------------------------------------------------------------
// ws layout (bytes):
//   DEG   @ 0         : 200000 f32 (deg -> inv_sqrt)          800000
//   CNT   @ 800000    : 50000 i32 row counts                  200000
//   CUR   @ 1000000   : 50000 i32 fill cursors                200000
//   BST   @ 1200000   : 50000 i32 bin starts                  200000
//   BSUM  @ 1400000   : 49 i32
//   BOFF  @ 1401024   : 49 i32
//   EREC  @ 1409024   : 3.2M int2 (packed col, coef)        25600000
//   Y     @ 27010048  : 4*50000*128 bf16                    51200000
//   XB    @ 78210048  : 50000*128 bf16                      12800000
//   WT    @ 91010048  : 5*128*128 bf16 [seg][n][k]            163840
// total ~91.2 MB (ws >= 103 MB per R1)
// ---------------------------------------------------------------------------
#define OFF_DEG  0
#define OFF_CNT  800000
#define OFF_CUR  1000000
#define OFF_BST  1200000
#define OFF_BSUM 1400000
#define OFF_BOFF 1401024
#define OFF_EREC 1409024
#define OFF_Y    27010048
#define OFF_XB   78210048
#define OFF_WT   91010048

typedef __attribute__((ext_vector_type(8))) short bf16x8;
typedef __attribute__((ext_vector_type(4))) float f32x4;

__device__ inline unsigned short f2bf(float f) {
    unsigned u = __float_as_uint(f);
    u += 0x7fffu + ((u >> 16) & 1u);
    return (unsigned short)(u >> 16);
}

// --- prep: X f32 -> bf16 -------------------------------------------------
__global__ __launch_bounds__(256) void k_prep_x(const float* __restrict__ X,
                                                unsigned short* __restrict__ Xb) {
    int id = blockIdx.x * 256 + threadIdx.x;        // 1.6M threads, 4 elems each
    float4 v = *(const float4*)(X + (size_t)id * 4);
    ushort4 h;
    h.x = f2bf(v.x); h.y = f2bf(v.y); h.z = f2bf(v.z); h.w = f2bf(v.w);
    *(ushort4*)(Xb + (size_t)id * 4) = h;
}

// --- prep: W (f32 [k][n]) -> Wt bf16 [seg][n][k]  (seg0=Wself, 1..4=Wrel) --
__global__ __launch_bounds__(256) void k_prep_w(const float* __restrict__ Wself,
                                                const float* __restrict__ Wrel,
                                                unsigned short* __restrict__ Wt) {
    int id = blockIdx.x * 256 + threadIdx.x;        // 81920 total
    int seg = id >> 14;
    int rem = id & 16383;
    int n = rem >> 7, k = rem & 127;
    float v = (seg == 0) ? Wself[k * 128 + n] : Wrel[(size_t)(seg - 1) * 16384 + k * 128 + n];
    Wt[id] = f2bf(v);
}

// --- histogram row counts + degree sums ------------------------------------
__global__ __launch_bounds__(256) void k_hist(const int* __restrict__ rows,
                                              const float* __restrict__ vals,
                                              float* __restrict__ deg,
                                              int* __restrict__ cnt) {
    int t = blockIdx.x * 256 + threadIdx.x;
    if (t >= NE) return;
    int r = t / N_EDGES;
    int row = rows[t];
    atomicAdd(&cnt[row], 1);
    unsafeAtomicAdd(&deg[r * N_NODES + row], vals[t]);
}

__global__ __launch_bounds__(256) void k_rsqrt(float* __restrict__ deg) {
    int t = blockIdx.x * 256 + threadIdx.x;
    if (t < NB) deg[t] = rsqrtf(fmaxf(deg[t], 1e-12f));
}

// --- scan over 50000 row counts -------------------------------------------
__global__ __launch_bounds__(256) void k_scanA(const int* __restrict__ cnt,
                                               int* __restrict__ bst,
                                               int* __restrict__ bsum) {
    __shared__ int s[256];
    int t = threadIdx.x;
    int base = blockIdx.x * SCAN_CHUNK + t * 4;
    int v0 = 0, v1 = 0, v2 = 0, v3 = 0;
    if (base + 3 < NBROW) {
        int4 v = *(const int4*)(cnt + base);
        v0 = v.x; v1 = v.y; v2 = v.z; v3 = v.w;
    } else {
        if (base     < NBROW) v0 = cnt[base];
        if (base + 1 < NBROW) v1 = cnt[base + 1];
        if (base + 2 < NBROW) v2 = cnt[base + 2];
        if (base + 3 < NBROW) v3 = cnt[base + 3];
    }
    int tsum = v0 + v1 + v2 + v3;
    s[t] = tsum;
    __syncthreads();
    for (int off = 1; off < 256; off <<= 1) {
        int x = (t >= off) ? s[t - off] : 0;
        __syncthreads();
        s[t] += x;
        __syncthreads();
    }
    int excl = s[t] - tsum;
    if (base     < NBROW) bst[base]     = excl;
    if (base + 1 < NBROW) bst[base + 1] = excl + v0;
    if (base + 2 < NBROW) bst[base + 2] = excl + v0 + v1;
    if (base + 3 < NBROW) bst[base + 3] = excl + v0 + v1 + v2;
    if (t == 255) bsum[blockIdx.x] = s[255];
}

__global__ __launch_bounds__(256) void k_scanB(const int* __restrict__ bsum,
                                               int* __restrict__ boff) {
    __shared__ int s[256];
    int t = threadIdx.x;
    int v = (t < NBLK2) ? bsum[t] : 0;
    s[t] = v;
    __syncthreads();
    for (int off = 1; off < 256; off <<= 1) {
        int x = (t >= off) ? s[t - off] : 0;
        __syncthreads();
        s[t] += x;
        __syncthreads();
    }
    if (t < NBLK2) boff[t] = s[t] - v;
}

// add block offsets; also materialize cursor copy for fill
__global__ __launch_bounds__(256) void k_scanC(int* __restrict__ bst,
                                               int* __restrict__ cursor,
                                               const int* __restrict__ boff) {
    int t = threadIdx.x;
    int base = blockIdx.x * SCAN_CHUNK + t * 4;
    int add = boff[blockIdx.x];
#pragma unroll
    for (int q = 0; q < 4; q++) {
        int idx = base + q;
        if (idx < NBROW) {
            int v = bst[idx] + add;
            bst[idx] = v;
            cursor[idx] = v;
        }
    }
}

// --- fill CSR records (packed col = r*N+col, coef) --------------------------
__global__ __launch_bounds__(256) void k_fill(const int* __restrict__ rows,
                                              const int* __restrict__ cols,
                                              const float* __restrict__ vals,
                                              const float* __restrict__ inv,
                                              int* __restrict__ cursor,
                                              int2* __restrict__ erec) {
    int t = blockIdx.x * 256 + threadIdx.x;
    if (t >= NE) return;
    int r = t / N_EDGES;
    int row = rows[t], col = cols[t];
    float coef = vals[t] * inv[r * N_NODES + row] * inv[r * N_NODES + col];
    int pos = atomicAdd(&cursor[row], 1);
    erec[pos] = make_int2(r * N_NODES + col, __float_as_int(coef));
}

// --- fused 5-panel MFMA GEMM ------------------------------------------------
// seg 0: out = X@Wself + bias (f32) ; seg r: Y[r-1] = X@Wrel[r-1] (bf16)
// BM=128, BN=128, K=128 (4 steps of 32). 4 waves in 2x2, each 64x64.
__global__ __launch_bounds__(256) void k_mm(const unsigned short* __restrict__ Xb,
                                            const unsigned short* __restrict__ Wt,
                                            const float* __restrict__ bias,
                                            float* __restrict__ out,
                                            unsigned short* __restrict__ Yb) {
    const int seg = blockIdx.y;
    const int m0 = blockIdx.x * 128;
    const int tid = threadIdx.x;
    const int wave = tid >> 6, lane = tid & 63;
    const int wm = wave >> 1, wn = wave & 1;

    __shared__ unsigned short Xs[128][40];   // 80B row stride: 16B aligned, 2-way banks
    __shared__ unsigned short Ws[128][40];   // [n][k]

    const f32x4 zero = {0.f, 0.f, 0.f, 0.f};
    f32x4 acc[4][4];
#pragma unroll
    for (int i = 0; i < 4; i++)
#pragma unroll
        for (int j = 0; j < 4; j++) acc[i][j] = zero;

    const unsigned short* Wseg = Wt + (size_t)seg * 16384;

    for (int k0 = 0; k0 < 128; k0 += 32) {
        // stage X tile 128x32 and Wt tile 128x32 (16B chunks, 2 each per thread)
#pragma unroll
        for (int l = 0; l < 2; l++) {
            int id = tid + l * 256;
            int row = id >> 2, c4 = id & 3;        // c4: 8-elem chunk
            int gr = m0 + row;
            int4 v = make_int4(0, 0, 0, 0);
            if (gr < N_NODES)
                v = *(const int4*)(Xb + (size_t)gr * 128 + k0 + c4 * 8);
            *(int4*)&Xs[row][c4 * 8] = v;
            int4 w = *(const int4*)(Wseg + (size_t)row * 128 + k0 + c4 * 8);
            *(int4*)&Ws[row][c4 * 8] = w;
        }
        __syncthreads();

        bf16x8 a[4], b[4];
        int kb = (lane >> 4) * 8;
        int lr = lane & 15;
#pragma unroll
        for (int i = 0; i < 4; i++)
            a[i] = *(const bf16x8*)&Xs[wm * 64 + i * 16 + lr][kb];
#pragma unroll
        for (int j = 0; j < 4; j++)
            b[j] = *(const bf16x8*)&Ws[wn * 64 + j * 16 + lr][kb];
#pragma unroll
        for (int i = 0; i < 4; i++)
#pragma unroll
            for (int j = 0; j < 4; j++)
                acc[i][j] = __builtin_amdgcn_mfma_f32_16x16x32_bf16(a[i], b[j], acc[i][j], 0, 0, 0);
        __syncthreads();
    }

    // epilogue: D[row=(lane>>4)*4+v][col=lane&15] per 16x16 frag
    const int lrow = (lane >> 4) * 4;
    const int lcol = lane & 15;
    if (seg == 0) {
#pragma unroll
        for (int i = 0; i < 4; i++) {
#pragma unroll
            for (int j = 0; j < 4; j++) {
                int gc = wn * 64 + j * 16 + lcol;
                float bv = bias[gc];
#pragma unroll
                for (int v = 0; v < 4; v++) {
                    int gr = m0 + wm * 64 + i * 16 + lrow + v;
                    if (gr < N_NODES)
                        out[(size_t)gr * 128 + gc] = acc[i][j][v] + bv;
                }
            }
        }
    } else {
        unsigned short* Yseg = Yb + (size_t)(seg - 1) * N_NODES * 128;
#pragma unroll
        for (int i = 0; i < 4; i++) {
#pragma unroll
            for (int j = 0; j < 4; j++) {
                int gc = wn * 64 + j * 16 + lcol;
#pragma unroll
                for (int v = 0; v < 4; v++) {
                    int gr = m0 + wm * 64 + i * 16 + lrow + v;
                    if (gr < N_NODES)
                        Yseg[(size_t)gr * 128 + gc] = f2bf(acc[i][j][v]);
                }
            }
        }
    }
}

// --- gather: one wave per row, lane-batched records + readlane broadcast ----
__global__ __launch_bounds__(256, 4) void k_gather(const int* __restrict__ bst,
                                                   const int2* __restrict__ erec,
                                                   const unsigned int* __restrict__ Y2,
                                                   float* __restrict__ out) {
    const int wid = threadIdx.x >> 6;
    const int lane = threadIdx.x & 63;
    const int row = blockIdx.x * 4 + wid;
    if (row >= N_NODES) return;

    const int start = bst[row];
    const int end = (row + 1 < N_NODES) ? bst[row + 1] : NE;

    float ax = 0.f, ay = 0.f;
    for (int base = start; base < end; base += 64) {
        const int rem = end - base;
        int2 rec = make_int2(0, 0);
        if (lane < rem) rec = erec[base + lane];
        if (rem >= 64) {
#pragma unroll
            for (int i = 0; i < 64; ++i) {
                int pc = __builtin_amdgcn_readlane(rec.x, i);
                float cf = __int_as_float(__builtin_amdgcn_readlane(rec.y, i));
                unsigned int y = Y2[(size_t)pc * 64 + lane];
                ax = fmaf(cf, __uint_as_float(y << 16), ax);
                ay = fmaf(cf, __uint_as_float(y & 0xffff0000u), ay);
            }
        } else {
            for (int i = 0; i < rem; ++i) {
                int pc = __builtin_amdgcn_readlane(rec.x, i);
                float cf = __int_as_float(__builtin_amdgcn_readlane(rec.y, i));
                unsigned int y = Y2[(size_t)pc * 64 + lane];
                ax = fmaf(cf, __uint_as_float(y << 16), ax);
                ay = fmaf(cf, __uint_as_float(y & 0xffff0000u), ay);
            }
        }
    }
    float2* op = (float2*)(out + (size_t)row * D) + lane;
    float2 o = *op;
    o.x += ax;
    o.y += ay;
    *op = o;
}

extern "C" void kernel_launch(void* const* d_in, const int* in_sizes, int n_in,
                              void* d_out, int out_size, void* d_ws, size_t ws_size,
                              hipStream_t stream) {
    const float* X     = (const float*)d_in[0];
    const int*   rows  = (const int*)d_in[1];
    const int*   cols  = (const int*)d_in[2];
    const float* vals  = (const float*)d_in[3];
    const float* Wrel  = (const float*)d_in[4];
    const float* Wself = (const float*)d_in[5];
    const float* bias  = (const float*)d_in[6];
    float* out = (float*)d_out;

    char* ws = (char*)d_ws;
    float* deg    = (float*)(ws + OFF_DEG);
    int*   cnt    = (int*)(ws + OFF_CNT);
    int*   cursor = (int*)(ws + OFF_CUR);
    int*   bst    = (int*)(ws + OFF_BST);
    int*   bsum   = (int*)(ws + OFF_BSUM);
    int*   boff   = (int*)(ws + OFF_BOFF);
    int2*  erec   = (int2*)(ws + OFF_EREC);
    unsigned short* Yb = (unsigned short*)(ws + OFF_Y);
    unsigned short* Xb = (unsigned short*)(ws + OFF_XB);
    unsigned short* Wt = (unsigned short*)(ws + OFF_WT);

    // zero deg (800KB) + cnt (200KB), contiguous
    hipMemsetAsync(ws, 0, 1000000, stream);

    k_prep_x<<<6250, 256, 0, stream>>>(X, Xb);
    k_prep_w<<<320, 256, 0, stream>>>(Wself, Wrel, Wt);

    k_hist<<<(NE + 255) / 256, 256, 0, stream>>>(rows, vals, deg, cnt);
    k_rsqrt<<<(NB + 255) / 256, 256, 0, stream>>>(deg);
    k_scanA<<<NBLK2, 256, 0, stream>>>(cnt, bst, bsum);
    k_scanB<<<1, 256, 0, stream>>>(bsum, boff);
    k_scanC<<<NBLK2, 256, 0, stream>>>(bst, cursor, boff);

    dim3 ggrid((N_NODES + 127) / 128, N_REL + 1);
    k_mm<<<ggrid, 256, 0, stream>>>(Xb, Wt, bias, out, Yb);

    k_fill<<<(NE + 255) / 256, 256, 0, stream>>>(rows, cols, vals, deg, cursor, erec);
    k_gather<<<(N_NODES + 3) / 4, 256, 0, stream>>>(bst, erec, (const unsigned int*)Yb, out);
}

// Round 4
// 487.514 us; speedup vs baseline: 3.2008x; 1.2882x over previous
//
#include <hip/hip_runtime.h>
#include <hip/hip_bf16.h>

#define N_NODES 50000
#define N_EDGES 800000
#define N_REL   4
#define D       128
#define NB      (N_REL * N_NODES)   // 200000 (rel,row) bins
#define NE      (N_REL * N_EDGES)   // 3200000 edges

#define SCAN_CHUNK 1024
#define NBLK ((NB + SCAN_CHUNK - 1) / SCAN_CHUNK)   // 196 (scan over 200000)

// ---------------------------------------------------------------------------
// ws layout (bytes):
//   H     @ 0        : 4 reps x 200000 u64 packed hist       6400000
//   INV   @ 6400000  : 200000 f32 inv_sqrt(deg)               800000
//   CNT2  @ 7200000  : 200000 i32 counts per (row,rep)        800000
//   CUR   @ 8000000  : 200000 i32 fill cursors                800000
//   BST   @ 8800000  : 200000 i32 bin starts                  800000
//   BSUM  @ 9600000  : 196 i32
//   BOFF  @ 9601024  : 196 i32
//   EREC  @ 9602048  : 3.2M int2 (packed col, coef)         25600000
//   Y     @ 35202048 : 4*50000*128 bf16                     51200000
//   XB    @ 86402048 : 50000*128 bf16                       12800000
//   WT    @ 99202048 : 5*128*128 bf16 [seg][n][k]             163840
// total ~99.4 MB (ws >= 103.2 MB per R1)
// ---------------------------------------------------------------------------
#define OFF_H    0
#define OFF_INV  6400000
#define OFF_CNT2 7200000
#define OFF_CUR  8000000
#define OFF_BST  8800000
#define OFF_BSUM 9600000
#define OFF_BOFF 9601024
#define OFF_EREC 9602048
#define OFF_Y    35202048
#define OFF_XB   86402048
#define OFF_WT   99202048

typedef __attribute__((ext_vector_type(8))) short bf16x8;
typedef __attribute__((ext_vector_type(4))) float f32x4;

__device__ inline unsigned short f2bf(float f) {
    unsigned u = __float_as_uint(f);
    u += 0x7fffu + ((u >> 16) & 1u);
    return (unsigned short)(u >> 16);
}

// --- prep: X f32 -> bf16 ---------------------------------------------------
__global__ __launch_bounds__(256) void k_prep_x(const float* __restrict__ X,
                                                unsigned short* __restrict__ Xb) {
    int id = blockIdx.x * 256 + threadIdx.x;
    float4 v = *(const float4*)(X + (size_t)id * 4);
    ushort4 h;
    h.x = f2bf(v.x); h.y = f2bf(v.y); h.z = f2bf(v.z); h.w = f2bf(v.w);
    *(ushort4*)(Xb + (size_t)id * 4) = h;
}

// --- prep: W (f32 [k][n]) -> Wt bf16 [seg][n][k] ---------------------------
__global__ __launch_bounds__(256) void k_prep_w(const float* __restrict__ Wself,
                                                const float* __restrict__ Wrel,
                                                unsigned short* __restrict__ Wt) {
    int id = blockIdx.x * 256 + threadIdx.x;
    int seg = id >> 14;
    int rem = id & 16383;
    int n = rem >> 7, k = rem & 127;
    float v = (seg == 0) ? Wself[k * 128 + n] : Wrel[(size_t)(seg - 1) * 16384 + k * 128 + n];
    Wt[id] = f2bf(v);
}

// --- packed histogram: one u64 atomic per edge -----------------------------
// H[rep][r*N+row] += (1<<40) | round(val * 2^24)
__global__ __launch_bounds__(256) void k_hist(const int* __restrict__ rows,
                                              const float* __restrict__ vals,
                                              unsigned long long* __restrict__ H) {
    int t = blockIdx.x * 256 + threadIdx.x;
    if (t >= NE) return;
    int rep = blockIdx.x & 3;
    int r = t / N_EDGES;
    int row = rows[t];
    unsigned long long pkt = (1ull << 40) |
        (unsigned long long)__float2uint_rn(vals[t] * 16777216.0f);
    atomicAdd(&H[(size_t)rep * NB + r * N_NODES + row], pkt);
}

// --- inv[bin] = rsqrt(deg), deg from low-40 fixed-point fields -------------
__global__ __launch_bounds__(256) void k_inv(const unsigned long long* __restrict__ H,
                                             float* __restrict__ inv) {
    int bin = blockIdx.x * 256 + threadIdx.x;
    if (bin >= NB) return;
    const unsigned long long m = (1ull << 40) - 1;
    unsigned long long dsum = (H[bin] & m) + (H[NB + bin] & m) +
                              (H[2 * NB + bin] & m) + (H[3 * NB + bin] & m);
    float deg = (float)dsum * (1.0f / 16777216.0f);
    inv[bin] = rsqrtf(fmaxf(deg, 1e-12f));
}

// --- cnt2[row*4+rep] = sum over rels of count fields -----------------------
__global__ __launch_bounds__(256) void k_cnt(const unsigned long long* __restrict__ H,
                                             int* __restrict__ cnt2) {
    int idx = blockIdx.x * 256 + threadIdx.x;
    if (idx >= NB) return;
    int row = idx >> 2, rep = idx & 3;
    const unsigned long long* Hr = H + (size_t)rep * NB;
    int c = (int)((Hr[row] >> 40) + (Hr[N_NODES + row] >> 40) +
                  (Hr[2 * N_NODES + row] >> 40) + (Hr[3 * N_NODES + row] >> 40));
    cnt2[idx] = c;
}

// --- scan over 200000 (row,rep) counts -------------------------------------
__global__ __launch_bounds__(256) void k_scanA(const int* __restrict__ cnt,
                                               int* __restrict__ bst,
                                               int* __restrict__ bsum) {
    __shared__ int s[256];
    int t = threadIdx.x;
    int base = blockIdx.x * SCAN_CHUNK + t * 4;
    int v0 = 0, v1 = 0, v2 = 0, v3 = 0;
    if (base + 3 < NB) {
        int4 v = *(const int4*)(cnt + base);
        v0 = v.x; v1 = v.y; v2 = v.z; v3 = v.w;
    } else {
        if (base     < NB) v0 = cnt[base];
        if (base + 1 < NB) v1 = cnt[base + 1];
        if (base + 2 < NB) v2 = cnt[base + 2];
        if (base + 3 < NB) v3 = cnt[base + 3];
    }
    int tsum = v0 + v1 + v2 + v3;
    s[t] = tsum;
    __syncthreads();
    for (int off = 1; off < 256; off <<= 1) {
        int x = (t >= off) ? s[t - off] : 0;
        __syncthreads();
        s[t] += x;
        __syncthreads();
    }
    int excl = s[t] - tsum;
    if (base     < NB) bst[base]     = excl;
    if (base + 1 < NB) bst[base + 1] = excl + v0;
    if (base + 2 < NB) bst[base + 2] = excl + v0 + v1;
    if (base + 3 < NB) bst[base + 3] = excl + v0 + v1 + v2;
    if (t == 255) bsum[blockIdx.x] = s[255];
}

__global__ __launch_bounds__(256) void k_scanB(const int* __restrict__ bsum,
                                               int* __restrict__ boff) {
    __shared__ int s[256];
    int t = threadIdx.x;
    int v = (t < NBLK) ? bsum[t] : 0;
    s[t] = v;
    __syncthreads();
    for (int off = 1; off < 256; off <<= 1) {
        int x = (t >= off) ? s[t - off] : 0;
        __syncthreads();
        s[t] += x;
        __syncthreads();
    }
    if (t < NBLK) boff[t] = s[t] - v;
}

__global__ __launch_bounds__(256) void k_scanC(int* __restrict__ bst,
                                               int* __restrict__ cursor,
                                               const int* __restrict__ boff) {
    int t = threadIdx.x;
    int base = blockIdx.x * SCAN_CHUNK + t * 4;
    int add = boff[blockIdx.x];
#pragma unroll
    for (int q = 0; q < 4; q++) {
        int idx = base + q;
        if (idx < NB) {
            int v = bst[idx] + add;
            bst[idx] = v;
            cursor[idx] = v;
        }
    }
}

// --- fill CSR records (packed col = r*N+col, coef) -------------------------
__global__ __launch_bounds__(256) void k_fill(const int* __restrict__ rows,
                                              const int* __restrict__ cols,
                                              const float* __restrict__ vals,
                                              const float* __restrict__ inv,
                                              int* __restrict__ cursor,
                                              int2* __restrict__ erec) {
    int t = blockIdx.x * 256 + threadIdx.x;
    if (t >= NE) return;
    int rep = blockIdx.x & 3;
    int r = t / N_EDGES;
    int row = rows[t], col = cols[t];
    float coef = vals[t] * inv[r * N_NODES + row] * inv[r * N_NODES + col];
    int pos = atomicAdd(&cursor[row * 4 + rep], 1);
    erec[pos] = make_int2(r * N_NODES + col, __float_as_int(coef));
}

// --- fused 5-panel MFMA GEMM -----------------------------------------------
__global__ __launch_bounds__(256) void k_mm(const unsigned short* __restrict__ Xb,
                                            const unsigned short* __restrict__ Wt,
                                            const float* __restrict__ bias,
                                            float* __restrict__ out,
                                            unsigned short* __restrict__ Yb) {
    const int seg = blockIdx.y;
    const int m0 = blockIdx.x * 128;
    const int tid = threadIdx.x;
    const int wave = tid >> 6, lane = tid & 63;
    const int wm = wave >> 1, wn = wave & 1;

    __shared__ unsigned short Xs[128][40];
    __shared__ unsigned short Ws[128][40];

    const f32x4 zero = {0.f, 0.f, 0.f, 0.f};
    f32x4 acc[4][4];
#pragma unroll
    for (int i = 0; i < 4; i++)
#pragma unroll
        for (int j = 0; j < 4; j++) acc[i][j] = zero;

    const unsigned short* Wseg = Wt + (size_t)seg * 16384;

    for (int k0 = 0; k0 < 128; k0 += 32) {
#pragma unroll
        for (int l = 0; l < 2; l++) {
            int id = tid + l * 256;
            int row = id >> 2, c4 = id & 3;
            int gr = m0 + row;
            int4 v = make_int4(0, 0, 0, 0);
            if (gr < N_NODES)
                v = *(const int4*)(Xb + (size_t)gr * 128 + k0 + c4 * 8);
            *(int4*)&Xs[row][c4 * 8] = v;
            int4 w = *(const int4*)(Wseg + (size_t)row * 128 + k0 + c4 * 8);
            *(int4*)&Ws[row][c4 * 8] = w;
        }
        __syncthreads();

        bf16x8 a[4], b[4];
        int kb = (lane >> 4) * 8;
        int lr = lane & 15;
#pragma unroll
        for (int i = 0; i < 4; i++)
            a[i] = *(const bf16x8*)&Xs[wm * 64 + i * 16 + lr][kb];
#pragma unroll
        for (int j = 0; j < 4; j++)
            b[j] = *(const bf16x8*)&Ws[wn * 64 + j * 16 + lr][kb];
#pragma unroll
        for (int i = 0; i < 4; i++)
#pragma unroll
            for (int j = 0; j < 4; j++)
                acc[i][j] = __builtin_amdgcn_mfma_f32_16x16x32_bf16(a[i], b[j], acc[i][j], 0, 0, 0);
        __syncthreads();
    }

    const int lrow = (lane >> 4) * 4;
    const int lcol = lane & 15;
    if (seg == 0) {
#pragma unroll
        for (int i = 0; i < 4; i++) {
#pragma unroll
            for (int j = 0; j < 4; j++) {
                int gc = wn * 64 + j * 16 + lcol;
                float bv = bias[gc];
#pragma unroll
                for (int v = 0; v < 4; v++) {
                    int gr = m0 + wm * 64 + i * 16 + lrow + v;
                    if (gr < N_NODES)
                        out[(size_t)gr * 128 + gc] = acc[i][j][v] + bv;
                }
            }
        }
    } else {
        unsigned short* Yseg = Yb + (size_t)(seg - 1) * N_NODES * 128;
#pragma unroll
        for (int i = 0; i < 4; i++) {
#pragma unroll
            for (int j = 0; j < 4; j++) {
                int gc = wn * 64 + j * 16 + lcol;
#pragma unroll
                for (int v = 0; v < 4; v++) {
                    int gr = m0 + wm * 64 + i * 16 + lrow + v;
                    if (gr < N_NODES)
                        Yseg[(size_t)gr * 128 + gc] = f2bf(acc[i][j][v]);
                }
            }
        }
    }
}

// --- gather: one wave per row, lane-batched records + readlane broadcast ---
__global__ __launch_bounds__(256, 4) void k_gather(const int* __restrict__ bst,
                                                   const int2* __restrict__ erec,
                                                   const unsigned int* __restrict__ Y2,
                                                   float* __restrict__ out) {
    const int wid = threadIdx.x >> 6;
    const int lane = threadIdx.x & 63;
    const int row = blockIdx.x * 4 + wid;
    if (row >= N_NODES) return;

    const int start = bst[row * 4];
    const int end = (row + 1 < N_NODES) ? bst[(row + 1) * 4] : NE;

    float ax = 0.f, ay = 0.f;
    for (int base = start; base < end; base += 64) {
        const int rem = end - base;
        int2 rec = make_int2(0, 0);
        if (lane < rem) rec = erec[base + lane];
        if (rem >= 64) {
#pragma unroll
            for (int i = 0; i < 64; ++i) {
                int pc = __builtin_amdgcn_readlane(rec.x, i);
                float cf = __int_as_float(__builtin_amdgcn_readlane(rec.y, i));
                unsigned int y = Y2[(size_t)pc * 64 + lane];
                ax = fmaf(cf, __uint_as_float(y << 16), ax);
                ay = fmaf(cf, __uint_as_float(y & 0xffff0000u), ay);
            }
        } else {
            for (int i = 0; i < rem; ++i) {
                int pc = __builtin_amdgcn_readlane(rec.x, i);
                float cf = __int_as_float(__builtin_amdgcn_readlane(rec.y, i));
                unsigned int y = Y2[(size_t)pc * 64 + lane];
                ax = fmaf(cf, __uint_as_float(y << 16), ax);
                ay = fmaf(cf, __uint_as_float(y & 0xffff0000u), ay);
            }
        }
    }
    float2* op = (float2*)(out + (size_t)row * D) + lane;
    float2 o = *op;
    o.x += ax;
    o.y += ay;
    *op = o;
}

extern "C" void kernel_launch(void* const* d_in, const int* in_sizes, int n_in,
                              void* d_out, int out_size, void* d_ws, size_t ws_size,
                              hipStream_t stream) {
    const float* X     = (const float*)d_in[0];
    const int*   rows  = (const int*)d_in[1];
    const int*   cols  = (const int*)d_in[2];
    const float* vals  = (const float*)d_in[3];
    const float* Wrel  = (const float*)d_in[4];
    const float* Wself = (const float*)d_in[5];
    const float* bias  = (const float*)d_in[6];
    float* out = (float*)d_out;

    char* ws = (char*)d_ws;
    unsigned long long* H = (unsigned long long*)(ws + OFF_H);
    float* inv    = (float*)(ws + OFF_INV);
    int*   cnt2   = (int*)(ws + OFF_CNT2);
    int*   cursor = (int*)(ws + OFF_CUR);
    int*   bst    = (int*)(ws + OFF_BST);
    int*   bsum   = (int*)(ws + OFF_BSUM);
    int*   boff   = (int*)(ws + OFF_BOFF);
    int2*  erec   = (int2*)(ws + OFF_EREC);
    unsigned short* Yb = (unsigned short*)(ws + OFF_Y);
    unsigned short* Xb = (unsigned short*)(ws + OFF_XB);
    unsigned short* Wt = (unsigned short*)(ws + OFF_WT);

    // zero packed histogram (6.4 MB)
    hipMemsetAsync(ws, 0, 6400000, stream);

    k_prep_x<<<6250, 256, 0, stream>>>(X, Xb);
    k_prep_w<<<320, 256, 0, stream>>>(Wself, Wrel, Wt);

    k_hist<<<(NE + 255) / 256, 256, 0, stream>>>(rows, vals, H);
    k_inv<<<(NB + 255) / 256, 256, 0, stream>>>(H, inv);
    k_cnt<<<(NB + 255) / 256, 256, 0, stream>>>(H, cnt2);
    k_scanA<<<NBLK, 256, 0, stream>>>(cnt2, bst, bsum);
    k_scanB<<<1, 256, 0, stream>>>(bsum, boff);
    k_scanC<<<NBLK, 256, 0, stream>>>(bst, cursor, boff);

    dim3 ggrid((N_NODES + 127) / 128, N_REL + 1);
    k_mm<<<ggrid, 256, 0, stream>>>(Xb, Wt, bias, out, Yb);

    k_fill<<<(NE + 255) / 256, 256, 0, stream>>>(rows, cols, vals, inv, cursor, erec);
    k_gather<<<(N_NODES + 3) / 4, 256, 0, stream>>>(bst, erec, (const unsigned int*)Yb, out);
}

// Round 5
// 441.621 us; speedup vs baseline: 3.5334x; 1.1039x over previous
//
#include <hip/hip_runtime.h>
#include <hip/hip_bf16.h>

#define N_NODES 50000
#define N_EDGES 800000
#define N_REL   4
#define D       128
#define NB      (N_REL * N_NODES)   // 200000 (rel,row) bins
#define NE      (N_REL * N_EDGES)   // 3200000 edges
#define NREP    4
#define NB2     (N_NODES * 16)      // 800000 (row,rep,rel) bins

#define SCAN_CHUNK 1024
#define NBLK ((NB2 + SCAN_CHUNK - 1) / SCAN_CHUNK)   // 782

// ---------------------------------------------------------------------------
// ws layout (bytes):
//   H     @ 0         : 4 reps x 200000 u64 packed hist      6,400,000
//   INV   @ 6400000   : 200000 f32 inv_sqrt(deg)               800,000
//   BST   @ 7200000   : 800000 i32 (counts, scanned in place) 3,200,000
//   BSUM  @ 10400000  : 782 i32 (pad 4K)
//   BOFF  @ 10404096  : 782 i32 (pad 4K)
//   EREC  @ 10408192  : 3.2M int2 (packed col, coef)        25,600,000
//   Y     @ 36008192  : 4*50000*128 bf16                    51,200,000
//   XB    @ 87208192  : 50000*128 bf16; RANK aliases after mm 12,800,000
//   WT    @ 100008192 : 5*128*128 bf16 [seg][n][k]             163,840
// total ~100.2 MB (under the 103.2 MB proven watermark from R1)
// ---------------------------------------------------------------------------
#define OFF_H    0
#define OFF_INV  6400000
#define OFF_BST  7200000
#define OFF_BSUM 10400000
#define OFF_BOFF 10404096
#define OFF_EREC 10408192
#define OFF_Y    36008192
#define OFF_XB   87208192
#define OFF_WT   100008192

typedef __attribute__((ext_vector_type(8))) short bf16x8;
typedef __attribute__((ext_vector_type(4))) float f32x4;

__device__ inline unsigned short f2bf(float f) {
    unsigned u = __float_as_uint(f);
    u += 0x7fffu + ((u >> 16) & 1u);
    return (unsigned short)(u >> 16);
}

// --- prep: X f32 -> bf16 ---------------------------------------------------
__global__ __launch_bounds__(256) void k_prep_x(const float* __restrict__ X,
                                                unsigned short* __restrict__ Xb) {
    int id = blockIdx.x * 256 + threadIdx.x;
    float4 v = *(const float4*)(X + (size_t)id * 4);
    ushort4 h;
    h.x = f2bf(v.x); h.y = f2bf(v.y); h.z = f2bf(v.z); h.w = f2bf(v.w);
    *(ushort4*)(Xb + (size_t)id * 4) = h;
}

// --- prep: W (f32 [k][n]) -> Wt bf16 [seg][n][k] ---------------------------
__global__ __launch_bounds__(256) void k_prep_w(const float* __restrict__ Wself,
                                                const float* __restrict__ Wrel,
                                                unsigned short* __restrict__ Wt) {
    int id = blockIdx.x * 256 + threadIdx.x;
    int seg = id >> 14;
    int rem = id & 16383;
    int n = rem >> 7, k = rem & 127;
    float v = (seg == 0) ? Wself[k * 128 + n] : Wrel[(size_t)(seg - 1) * 16384 + k * 128 + n];
    Wt[id] = f2bf(v);
}

// --- packed histogram: one u64 atomic per edge; old value gives rank -------
// H[rep][r*N+row] += (1<<40) | round(val * 2^24); rank = old >> 40
__global__ __launch_bounds__(256) void k_hist(const int* __restrict__ rows,
                                              const float* __restrict__ vals,
                                              unsigned long long* __restrict__ H,
                                              unsigned int* __restrict__ rank) {
    int t = blockIdx.x * 256 + threadIdx.x;
    if (t >= NE) return;
    int rep = blockIdx.x & (NREP - 1);
    int r = t / N_EDGES;
    int row = rows[t];
    unsigned long long pkt = (1ull << 40) |
        (unsigned long long)__float2uint_rn(vals[t] * 16777216.0f);
    unsigned long long old = atomicAdd(&H[(size_t)rep * NB + r * N_NODES + row], pkt);
    rank[t] = (unsigned int)(old >> 40);
}

// --- inv[bin] = rsqrt(deg), deg from low-40 fixed-point fields -------------
__global__ __launch_bounds__(256) void k_inv(const unsigned long long* __restrict__ H,
                                             float* __restrict__ inv) {
    int bin = blockIdx.x * 256 + threadIdx.x;   // bin = r*N+row
    if (bin >= NB) return;
    const unsigned long long m = (1ull << 40) - 1;
    unsigned long long dsum = (H[bin] & m) + (H[NB + bin] & m) +
                              (H[2 * NB + bin] & m) + (H[3 * NB + bin] & m);
    float deg = (float)dsum * (1.0f / 16777216.0f);
    inv[bin] = rsqrtf(fmaxf(deg, 1e-12f));
}

// --- cnt[row*16 + rep*4 + rel] = count field of H[rep][rel*N+row] ----------
__global__ __launch_bounds__(256) void k_cnt(const unsigned long long* __restrict__ H,
                                             int* __restrict__ cnt) {
    int idx = blockIdx.x * 256 + threadIdx.x;
    if (idx >= NB2) return;
    int row = idx >> 4, rep = (idx >> 2) & 3, rel = idx & 3;
    cnt[idx] = (int)(H[(size_t)rep * NB + rel * N_NODES + row] >> 40);
}

// --- scan over 800000 (row,rep,rel) counts, in place -----------------------
__global__ __launch_bounds__(256) void k_scanA(int* __restrict__ bst,
                                               int* __restrict__ bsum) {
    __shared__ int s[256];
    int t = threadIdx.x;
    int base = blockIdx.x * SCAN_CHUNK + t * 4;
    int v0 = 0, v1 = 0, v2 = 0, v3 = 0;
    if (base + 3 < NB2) {
        int4 v = *(const int4*)(bst + base);
        v0 = v.x; v1 = v.y; v2 = v.z; v3 = v.w;
    } else {
        if (base     < NB2) v0 = bst[base];
        if (base + 1 < NB2) v1 = bst[base + 1];
        if (base + 2 < NB2) v2 = bst[base + 2];
        if (base + 3 < NB2) v3 = bst[base + 3];
    }
    int tsum = v0 + v1 + v2 + v3;
    s[t] = tsum;
    __syncthreads();
    for (int off = 1; off < 256; off <<= 1) {
        int x = (t >= off) ? s[t - off] : 0;
        __syncthreads();
        s[t] += x;
        __syncthreads();
    }
    int excl = s[t] - tsum;
    if (base     < NB2) bst[base]     = excl;
    if (base + 1 < NB2) bst[base + 1] = excl + v0;
    if (base + 2 < NB2) bst[base + 2] = excl + v0 + v1;
    if (base + 3 < NB2) bst[base + 3] = excl + v0 + v1 + v2;
    if (t == 255) bsum[blockIdx.x] = s[255];
}

// scan 782 block sums (single block, 4 per thread)
__global__ __launch_bounds__(256) void k_scanB(const int* __restrict__ bsum,
                                               int* __restrict__ boff) {
    __shared__ int s[256];
    int t = threadIdx.x;
    int b = t * 4;
    int v0 = (b     < NBLK) ? bsum[b]     : 0;
    int v1 = (b + 1 < NBLK) ? bsum[b + 1] : 0;
    int v2 = (b + 2 < NBLK) ? bsum[b + 2] : 0;
    int v3 = (b + 3 < NBLK) ? bsum[b + 3] : 0;
    int tsum = v0 + v1 + v2 + v3;
    s[t] = tsum;
    __syncthreads();
    for (int off = 1; off < 256; off <<= 1) {
        int x = (t >= off) ? s[t - off] : 0;
        __syncthreads();
        s[t] += x;
        __syncthreads();
    }
    int excl = s[t] - tsum;
    if (b     < NBLK) boff[b]     = excl;
    if (b + 1 < NBLK) boff[b + 1] = excl + v0;
    if (b + 2 < NBLK) boff[b + 2] = excl + v0 + v1;
    if (b + 3 < NBLK) boff[b + 3] = excl + v0 + v1 + v2;
}

__global__ __launch_bounds__(256) void k_scanC(int* __restrict__ bst,
                                               const int* __restrict__ boff) {
    int t = threadIdx.x;
    int base = blockIdx.x * SCAN_CHUNK + t * 4;
    int add = boff[blockIdx.x];
#pragma unroll
    for (int q = 0; q < 4; q++) {
        int idx = base + q;
        if (idx < NB2) bst[idx] += add;
    }
}

// --- fill CSR records, atomic-free: pos = bst[bin] + rank ------------------
__global__ __launch_bounds__(256) void k_fill(const int* __restrict__ rows,
                                              const int* __restrict__ cols,
                                              const float* __restrict__ vals,
                                              const float* __restrict__ inv,
                                              const int* __restrict__ bst,
                                              const unsigned int* __restrict__ rank,
                                              int2* __restrict__ erec) {
    int t = blockIdx.x * 256 + threadIdx.x;
    if (t >= NE) return;
    int rep = blockIdx.x & (NREP - 1);
    int r = t / N_EDGES;
    int row = rows[t], col = cols[t];
    float coef = vals[t] * inv[r * N_NODES + row] * inv[r * N_NODES + col];
    int pos = bst[row * 16 + rep * 4 + r] + (int)rank[t];
    erec[pos] = make_int2(r * N_NODES + col, __float_as_int(coef));
}

// --- fused 5-panel MFMA GEMM -----------------------------------------------
__global__ __launch_bounds__(256) void k_mm(const unsigned short* __restrict__ Xb,
                                            const unsigned short* __restrict__ Wt,
                                            const float* __restrict__ bias,
                                            float* __restrict__ out,
                                            unsigned short* __restrict__ Yb) {
    const int seg = blockIdx.y;
    const int m0 = blockIdx.x * 128;
    const int tid = threadIdx.x;
    const int wave = tid >> 6, lane = tid & 63;
    const int wm = wave >> 1, wn = wave & 1;

    __shared__ unsigned short Xs[128][40];
    __shared__ unsigned short Ws[128][40];

    const f32x4 zero = {0.f, 0.f, 0.f, 0.f};
    f32x4 acc[4][4];
#pragma unroll
    for (int i = 0; i < 4; i++)
#pragma unroll
        for (int j = 0; j < 4; j++) acc[i][j] = zero;

    const unsigned short* Wseg = Wt + (size_t)seg * 16384;

    for (int k0 = 0; k0 < 128; k0 += 32) {
#pragma unroll
        for (int l = 0; l < 2; l++) {
            int id = tid + l * 256;
            int row = id >> 2, c4 = id & 3;
            int gr = m0 + row;
            int4 v = make_int4(0, 0, 0, 0);
            if (gr < N_NODES)
                v = *(const int4*)(Xb + (size_t)gr * 128 + k0 + c4 * 8);
            *(int4*)&Xs[row][c4 * 8] = v;
            int4 w = *(const int4*)(Wseg + (size_t)row * 128 + k0 + c4 * 8);
            *(int4*)&Ws[row][c4 * 8] = w;
        }
        __syncthreads();

        bf16x8 a[4], b[4];
        int kb = (lane >> 4) * 8;
        int lr = lane & 15;
#pragma unroll
        for (int i = 0; i < 4; i++)
            a[i] = *(const bf16x8*)&Xs[wm * 64 + i * 16 + lr][kb];
#pragma unroll
        for (int j = 0; j < 4; j++)
            b[j] = *(const bf16x8*)&Ws[wn * 64 + j * 16 + lr][kb];
#pragma unroll
        for (int i = 0; i < 4; i++)
#pragma unroll
            for (int j = 0; j < 4; j++)
                acc[i][j] = __builtin_amdgcn_mfma_f32_16x16x32_bf16(a[i], b[j], acc[i][j], 0, 0, 0);
        __syncthreads();
    }

    const int lrow = (lane >> 4) * 4;
    const int lcol = lane & 15;
    if (seg == 0) {
#pragma unroll
        for (int i = 0; i < 4; i++) {
#pragma unroll
            for (int j = 0; j < 4; j++) {
                int gc = wn * 64 + j * 16 + lcol;
                float bv = bias[gc];
#pragma unroll
                for (int v = 0; v < 4; v++) {
                    int gr = m0 + wm * 64 + i * 16 + lrow + v;
                    if (gr < N_NODES)
                        out[(size_t)gr * 128 + gc] = acc[i][j][v] + bv;
                }
            }
        }
    } else {
        unsigned short* Yseg = Yb + (size_t)(seg - 1) * N_NODES * 128;
#pragma unroll
        for (int i = 0; i < 4; i++) {
#pragma unroll
            for (int j = 0; j < 4; j++) {
                int gc = wn * 64 + j * 16 + lcol;
#pragma unroll
                for (int v = 0; v < 4; v++) {
                    int gr = m0 + wm * 64 + i * 16 + lrow + v;
                    if (gr < N_NODES)
                        Yseg[(size_t)gr * 128 + gc] = f2bf(acc[i][j][v]);
                }
            }
        }
    }
}

// --- gather: one wave per row, lane-batched records + readlane broadcast ---
__global__ __launch_bounds__(256, 4) void k_gather(const int* __restrict__ bst,
                                                   const int2* __restrict__ erec,
                                                   const unsigned int* __restrict__ Y2,
                                                   float* __restrict__ out) {
    const int wid = threadIdx.x >> 6;
    const int lane = threadIdx.x & 63;
    const int row = blockIdx.x * 4 + wid;
    if (row >= N_NODES) return;

    const int start = bst[row * 16];
    const int end = (row + 1 < N_NODES) ? bst[(row + 1) * 16] : NE;

    float ax = 0.f, ay = 0.f;
    for (int base = start; base < end; base += 64) {
        const int rem = end - base;
        int2 rec = make_int2(0, 0);
        if (lane < rem) rec = erec[base + lane];
        if (rem >= 64) {
#pragma unroll
            for (int i = 0; i < 64; ++i) {
                int pc = __builtin_amdgcn_readlane(rec.x, i);
                float cf = __int_as_float(__builtin_amdgcn_readlane(rec.y, i));
                unsigned int y = Y2[(size_t)pc * 64 + lane];
                ax = fmaf(cf, __uint_as_float(y << 16), ax);
                ay = fmaf(cf, __uint_as_float(y & 0xffff0000u), ay);
            }
        } else {
            for (int i = 0; i < rem; ++i) {
                int pc = __builtin_amdgcn_readlane(rec.x, i);
                float cf = __int_as_float(__builtin_amdgcn_readlane(rec.y, i));
                unsigned int y = Y2[(size_t)pc * 64 + lane];
                ax = fmaf(cf, __uint_as_float(y << 16), ax);
                ay = fmaf(cf, __uint_as_float(y & 0xffff0000u), ay);
            }
        }
    }
    float2* op = (float2*)(out + (size_t)row * D) + lane;
    float2 o = *op;
    o.x += ax;
    o.y += ay;
    *op = o;
}

extern "C" void kernel_launch(void* const* d_in, const int* in_sizes, int n_in,
                              void* d_out, int out_size, void* d_ws, size_t ws_size,
                              hipStream_t stream) {
    const float* X     = (const float*)d_in[0];
    const int*   rows  = (const int*)d_in[1];
    const int*   cols  = (const int*)d_in[2];
    const float* vals  = (const float*)d_in[3];
    const float* Wrel  = (const float*)d_in[4];
    const float* Wself = (const float*)d_in[5];
    const float* bias  = (const float*)d_in[6];
    float* out = (float*)d_out;

    char* ws = (char*)d_ws;
    unsigned long long* H = (unsigned long long*)(ws + OFF_H);
    float* inv    = (float*)(ws + OFF_INV);
    int*   bst    = (int*)(ws + OFF_BST);
    int*   bsum   = (int*)(ws + OFF_BSUM);
    int*   boff   = (int*)(ws + OFF_BOFF);
    int2*  erec   = (int2*)(ws + OFF_EREC);
    unsigned short* Yb = (unsigned short*)(ws + OFF_Y);
    unsigned short* Xb = (unsigned short*)(ws + OFF_XB);
    unsigned short* Wt = (unsigned short*)(ws + OFF_WT);
    unsigned int* rank = (unsigned int*)(ws + OFF_XB);   // aliases Xb AFTER k_mm

    // zero packed histogram (6.4 MB)
    hipMemsetAsync(ws, 0, 6400000, stream);

    k_prep_x<<<6250, 256, 0, stream>>>(X, Xb);
    k_prep_w<<<320, 256, 0, stream>>>(Wself, Wrel, Wt);

    // GEMM first: Xb is dead afterwards, its space becomes the rank array
    dim3 ggrid((N_NODES + 127) / 128, N_REL + 1);
    k_mm<<<ggrid, 256, 0, stream>>>(Xb, Wt, bias, out, Yb);

    k_hist<<<(NE + 255) / 256, 256, 0, stream>>>(rows, vals, H, rank);
    k_inv<<<(NB + 255) / 256, 256, 0, stream>>>(H, inv);
    k_cnt<<<(NB2 + 255) / 256, 256, 0, stream>>>(H, bst);
    k_scanA<<<NBLK, 256, 0, stream>>>(bst, bsum);
    k_scanB<<<1, 256, 0, stream>>>(bsum, boff);
    k_scanC<<<NBLK, 256, 0, stream>>>(bst, boff);

    k_fill<<<(NE + 255) / 256, 256, 0, stream>>>(rows, cols, vals, inv, bst, rank, erec);
    k_gather<<<(N_NODES + 3) / 4, 256, 0, stream>>>(bst, erec, (const unsigned int*)Yb, out);
}